// Round 4
// baseline (1590.048 us; speedup 1.0000x reference)
//
#include <hip/hip_runtime.h>
#include <hip/hip_bf16.h>
#include <math.h>

#define IGNORE_INDEX (-100)
#define BETA 0.1f

typedef float f32x4 __attribute__((ext_vector_type(4)));
typedef int i32x8 __attribute__((ext_vector_type(8)));

static constexpr int Bsz = 8, T = 1024, H = 4096, V = 32000;
static constexpr int M = Bsz * T;       // 8192 tokens
static constexpr int BM = 256, BN = 256, BKB = 128;  // BKB = K-bytes per step (one MX MFMA)
static constexpr int MT = M / BM;       // 32
static constexpr int NT = V / BN;       // 125
static constexpr int NSTRIP = NT * 4;   // 500 strips of 64 cols
static constexpr int NKT = H / BKB;     // 32 K-steps
static constexpr int TILEB = BM * BKB;  // 32 KB per operand tile

// ------------------------------------------------- fp32 -> fp8 e4m3 (packed)
__global__ void cvt_fp8_kernel(const float* __restrict__ src,
                               uint2* __restrict__ dst, int n8) {
  int stride = gridDim.x * blockDim.x;
  for (int g = blockIdx.x * blockDim.x + threadIdx.x; g < n8; g += stride) {
    const float4* s = (const float4*)(src + (size_t)g * 8);
    float4 v0 = s[0], v1 = s[1];
    int r0 = __builtin_amdgcn_cvt_pk_fp8_f32(v0.x, v0.y, 0, false);
    r0 = __builtin_amdgcn_cvt_pk_fp8_f32(v0.z, v0.w, r0, true);
    int r1 = __builtin_amdgcn_cvt_pk_fp8_f32(v1.x, v1.y, 0, false);
    r1 = __builtin_amdgcn_cvt_pk_fp8_f32(v1.z, v1.w, r1, true);
    dst[g] = make_uint2((unsigned)r0, (unsigned)r1);
  }
}

__device__ inline void gload_lds16(const void* g, void* l) {
  __builtin_amdgcn_global_load_lds(
      (const __attribute__((address_space(1))) void*)g,
      (__attribute__((address_space(3))) void*)l, 16, 0, 0);
}

// read one 32-byte MX fragment (2x b128) through the XOR involution
__device__ inline i32x8 frag32(const unsigned char* rowp, int c0) {
  int4 lo = *(const int4*)(rowp + c0);
  int4 hi = *(const int4*)(rowp + (c0 ^ 16));
  return (i32x8){lo.x, lo.y, lo.z, lo.w, hi.x, hi.y, hi.z, hi.w};
}

#define MXMFMA(a, b, c) \
  __builtin_amdgcn_mfma_scale_f32_16x16x128_f8f6f4((a), (b), (c), 0, 0, 0, 0x7F7F7F7Fu, 0, 0x7F7F7F7Fu)
#define SBAR() asm volatile("s_barrier" ::: "memory")

// --------------------------- 256x256 phase-scheduled MX-fp8 GEMM + strip-LSE
// A: [M][H] fp8, W: [V][H] fp8 (B^T), bias fp32[V].
// Double-buffered 128 KiB LDS; 4 phases/K-step; raw s_barrier (no vmcnt
// drain); vmcnt(0) once per K-step; stages front-loaded in P0/P1.
__global__ __launch_bounds__(512, 2) void gemm_lse_kernel(
    const unsigned char* __restrict__ A, const unsigned char* __restrict__ W,
    const float* __restrict__ bias, const int* __restrict__ target,
    float2* __restrict__ partials, float* __restrict__ label_logit) {
  extern __shared__ unsigned char lds[];  // 2 x (A 32K + B 32K) = 128 KiB

  int bid = blockIdx.x;
  int swz = (bid & 7) * (MT * NT / 8) + (bid >> 3);  // bijective, 4000%8==0
  int mt = swz % MT;
  int nt = swz / MT;

  int tid = threadIdx.x;
  int l = tid & 63;
  int w = tid >> 6;            // 8 waves
  int wr = w >> 2, wc = w & 3; // 2x4 wave grid, 128x64 output each

  f32x4 acc[8][4];
#pragma unroll
  for (int m = 0; m < 8; ++m)
#pragma unroll
    for (int n = 0; n < 4; ++n) acc[m][n] = (f32x4){0.f, 0.f, 0.f, 0.f};

  // staging: thread covers (row = r*64 + w*8 + (l>>3), chunk l&7), source
  // chunk pre-swizzled so LDS[row][c] = G[row][c ^ (row&7)]
  int csrc = (l & 7) ^ ((l >> 3) & 7);
  const unsigned char* gA = A + (size_t)(mt * BM) * H;
  const unsigned char* gB = W + (size_t)(nt * BN) * H;
  size_t aOff = (size_t)(w * 8 + (l >> 3)) * H + csrc * 16;
  size_t bOff = aOff;  // same intra-tile pattern
  int ldst = w * 1024; // wave-uniform LDS dest base (HW adds lane*16)

  // fragment read bases: row&7 == l&7 for all frag rows
  int c0off = (((l >> 4) * 2) ^ (l & 7)) * 16;
  int aFragBase = (wr * 128 + (l & 15)) * BKB;
  int bFragBase = (wc * 64 + (l & 15)) * BKB;

  // prologue: stage K-step 0 into buf0
#pragma unroll
  for (int r = 0; r < 4; ++r) {
    gload_lds16(gA + aOff + (size_t)r * 64 * H, lds + r * 8192 + ldst);
    gload_lds16(gB + bOff + (size_t)r * 64 * H, lds + TILEB + r * 8192 + ldst);
  }
  asm volatile("s_waitcnt vmcnt(0)" ::: "memory");
  SBAR();

  for (int kt = 0; kt < NKT; ++kt) {
    const unsigned char* curA = lds + (kt & 1) * (2 * TILEB);
    const unsigned char* curB = curA + TILEB;
    unsigned char* nA = lds + ((kt & 1) ^ 1) * (2 * TILEB);
    unsigned char* nB = nA + TILEB;
    size_t kNext = (size_t)(kt + 1) * BKB;
    bool pf = (kt < NKT - 1);

    i32x8 bfr[4], a0, a1;
    // ---------------- P0: B all + A m0,m1 ; stage rounds 0,1
#pragma unroll
    for (int n = 0; n < 4; ++n) bfr[n] = frag32(curB + bFragBase + n * 2048, c0off);
    a0 = frag32(curA + aFragBase + 0 * 2048, c0off);
    a1 = frag32(curA + aFragBase + 1 * 2048, c0off);
    if (pf) {
      gload_lds16(gA + aOff + kNext, nA + ldst);
      gload_lds16(gA + aOff + (size_t)64 * H + kNext, nA + 8192 + ldst);
      gload_lds16(gB + bOff + kNext, nB + ldst);
      gload_lds16(gB + bOff + (size_t)64 * H + kNext, nB + 8192 + ldst);
    }
    SBAR();
    __builtin_amdgcn_s_setprio(1);
#pragma unroll
    for (int n = 0; n < 4; ++n) acc[0][n] = MXMFMA(a0, bfr[n], acc[0][n]);
#pragma unroll
    for (int n = 0; n < 4; ++n) acc[1][n] = MXMFMA(a1, bfr[n], acc[1][n]);
    __builtin_amdgcn_s_setprio(0);
    SBAR();
    // ---------------- P1: A m2,m3 ; stage rounds 2,3
    a0 = frag32(curA + aFragBase + 2 * 2048, c0off);
    a1 = frag32(curA + aFragBase + 3 * 2048, c0off);
    if (pf) {
      gload_lds16(gA + aOff + (size_t)128 * H + kNext, nA + 16384 + ldst);
      gload_lds16(gA + aOff + (size_t)192 * H + kNext, nA + 24576 + ldst);
      gload_lds16(gB + bOff + (size_t)128 * H + kNext, nB + 16384 + ldst);
      gload_lds16(gB + bOff + (size_t)192 * H + kNext, nB + 24576 + ldst);
    }
    SBAR();
    __builtin_amdgcn_s_setprio(1);
#pragma unroll
    for (int n = 0; n < 4; ++n) acc[2][n] = MXMFMA(a0, bfr[n], acc[2][n]);
#pragma unroll
    for (int n = 0; n < 4; ++n) acc[3][n] = MXMFMA(a1, bfr[n], acc[3][n]);
    __builtin_amdgcn_s_setprio(0);
    SBAR();
    // ---------------- P2: A m4,m5
    a0 = frag32(curA + aFragBase + 4 * 2048, c0off);
    a1 = frag32(curA + aFragBase + 5 * 2048, c0off);
    SBAR();
    __builtin_amdgcn_s_setprio(1);
#pragma unroll
    for (int n = 0; n < 4; ++n) acc[4][n] = MXMFMA(a0, bfr[n], acc[4][n]);
#pragma unroll
    for (int n = 0; n < 4; ++n) acc[5][n] = MXMFMA(a1, bfr[n], acc[5][n]);
    __builtin_amdgcn_s_setprio(0);
    SBAR();
    // ---------------- P3: A m6,m7 ; drain stage loads once per K-step
    a0 = frag32(curA + aFragBase + 6 * 2048, c0off);
    a1 = frag32(curA + aFragBase + 7 * 2048, c0off);
    SBAR();
    __builtin_amdgcn_s_setprio(1);
#pragma unroll
    for (int n = 0; n < 4; ++n) acc[6][n] = MXMFMA(a0, bfr[n], acc[6][n]);
#pragma unroll
    for (int n = 0; n < 4; ++n) acc[7][n] = MXMFMA(a1, bfr[n], acc[7][n]);
    __builtin_amdgcn_s_setprio(0);
    asm volatile("s_waitcnt vmcnt(0)" ::: "memory");
    SBAR();
  }

  // epilogue: bias add, per-row strip max/sumexp, label extraction
  int cbase = nt * BN + wc * 64 + (l & 15);
  float bv[4];
#pragma unroll
  for (int n = 0; n < 4; ++n) bv[n] = bias[cbase + n * 16];
  int strip = nt * 4 + wc;

#pragma unroll
  for (int m = 0; m < 8; ++m) {
#pragma unroll
    for (int j = 0; j < 4; ++j) {
      int tr = mt * BM + wr * 128 + m * 16 + (l >> 4) * 4 + j;
      float v0 = acc[m][0][j] + bv[0];
      float v1 = acc[m][1][j] + bv[1];
      float v2 = acc[m][2][j] + bv[2];
      float v3 = acc[m][3][j] + bv[3];
      float rmax = fmaxf(fmaxf(v0, v1), fmaxf(v2, v3));
#pragma unroll
      for (int off = 8; off; off >>= 1) rmax = fmaxf(rmax, __shfl_xor(rmax, off));
      float s = expf(v0 - rmax) + expf(v1 - rmax) + expf(v2 - rmax) + expf(v3 - rmax);
#pragma unroll
      for (int off = 8; off; off >>= 1) s += __shfl_xor(s, off);
      if ((l & 15) == 0) partials[(size_t)tr * NSTRIP + strip] = make_float2(rmax, s);
      int lbl = target[tr];
      if (lbl == cbase) label_logit[tr] = v0;
      else if (lbl == cbase + 16) label_logit[tr] = v1;
      else if (lbl == cbase + 32) label_logit[tr] = v2;
      else if (lbl == cbase + 48) label_logit[tr] = v3;
    }
  }
}

// ------------------------------------------------- per-token LSE combine
__global__ void lse_kernel(const float2* __restrict__ partials,
                           const float* __restrict__ label_logit,
                           const int* __restrict__ target,
                           float* __restrict__ token_logp) {
  int t = blockIdx.x;
  int lane = threadIdx.x;  // 64
  const float2* p = partials + (size_t)t * NSTRIP;
  float m = -INFINITY, s = 0.f;
  for (int i = lane; i < NSTRIP; i += 64) {
    float2 q = p[i];
    float nm = fmaxf(m, q.x);
    s = s * expf(m - nm) + q.y * expf(q.x - nm);
    m = nm;
  }
  float M2 = m;
#pragma unroll
  for (int off = 32; off; off >>= 1) M2 = fmaxf(M2, __shfl_xor(M2, off));
  float s2 = (m == -INFINITY) ? 0.f : s * expf(m - M2);
#pragma unroll
  for (int off = 32; off; off >>= 1) s2 += __shfl_xor(s2, off);
  if (lane == 0) {
    float lse = M2 + logf(s2);
    int lbl = target[t];
    token_logp[t] = (lbl != IGNORE_INDEX) ? (label_logit[t] - lse) : 0.f;
  }
}

// ------------------------------------------------- final scalar loss
__global__ void final_kernel(const float* __restrict__ token_logp,
                             const int* __restrict__ target,
                             float* __restrict__ out) {
  __shared__ float red[4];
  __shared__ float seq[8];
  int tid = threadIdx.x;  // 256
  int lane = tid & 63, w = tid >> 6;
  for (int b = 0; b < 8; ++b) {
    float s = 0.f;
    for (int t = tid; t < T; t += 256) s += token_logp[b * T + t];
#pragma unroll
    for (int off = 32; off; off >>= 1) s += __shfl_xor(s, off);
    if (lane == 0) red[w] = s;
    __syncthreads();
    if (tid == 0) seq[b] = red[0] + red[1] + red[2] + red[3];
    __syncthreads();
  }
  float c = 0.f;
  for (int t = tid; t < 4 * T; t += 256) c += (target[t] != IGNORE_INDEX) ? 1.f : 0.f;
#pragma unroll
  for (int off = 32; off; off >>= 1) c += __shfl_xor(c, off);
  if (lane == 0) red[w] = c;
  __syncthreads();
  if (tid == 0) {
    float cnt = red[0] + red[1] + red[2] + red[3];
    float nll = -(seq[0] + seq[1] + seq[2] + seq[3]) / cnt;
    float pref = 0.f;
    for (int i = 0; i < 4; ++i) {
      float d = BETA * (seq[i] - seq[i + 4]);
      float ls = fminf(d, 0.f) - log1pf(expf(-fabsf(d)));  // log_sigmoid(d)
      pref += -ls;
    }
    pref *= 0.25f;
    out[0] = nll + pref;
  }
}

extern "C" void kernel_launch(void* const* d_in, const int* in_sizes, int n_in,
                              void* d_out, int out_size, void* d_ws, size_t ws_size,
                              hipStream_t stream) {
  const float* lin_weight = (const float*)d_in[0];  // [V][H]
  const float* input = (const float*)d_in[1];       // [B][T][H]
  const int* target = (const int*)d_in[2];          // [B][T]
  const float* bias = (const float*)d_in[3];        // [V]
  float* out = (float*)d_out;

  char* ws = (char*)d_ws;
  unsigned char* Af8 = (unsigned char*)ws;
  size_t o = (size_t)M * H;
  unsigned char* Wf8 = (unsigned char*)(ws + o);
  o += (size_t)V * H;
  float2* partials = (float2*)(ws + o);
  o += (size_t)M * NSTRIP * 8;
  float* label_logit = (float*)(ws + o);
  o += (size_t)M * 4;
  float* token_logp = (float*)(ws + o);

  cvt_fp8_kernel<<<2048, 256, 0, stream>>>(input, (uint2*)Af8, M * H / 8);
  cvt_fp8_kernel<<<4096, 256, 0, stream>>>(lin_weight, (uint2*)Wf8, V * H / 8);
  gemm_lse_kernel<<<MT * NT, 512, 131072, stream>>>(Af8, Wf8, bias, target, partials, label_logit);
  lse_kernel<<<M, 64, 0, stream>>>(partials, label_logit, target, token_logp);
  final_kernel<<<1, 256, 0, stream>>>(token_logp, target, out);
}